// Round 5
// baseline (187.504 us; speedup 1.0000x reference)
//
#include <hip/hip_runtime.h>
#include <hip/hip_bf16.h>
#include <stdint.h>

// ---- problem constants (B=2, T=2048, C=1024, H=16, hs=64) ----
#define BSZ   2
#define TT    2048
#define NH    16
#define HS    64
#define CC    1024
#define C3    3072
#define MT    4096            // B*T rows
#define E10   4.5399929762484854e-05f   // exp(-10)
#define SCL2  0.1803368801111204f       // 0.125 * log2(e)

typedef __bf16 bf16;
typedef __bf16 bf16x8 __attribute__((ext_vector_type(8)));
typedef float  f32x4  __attribute__((ext_vector_type(4)));
typedef short  s16x4  __attribute__((ext_vector_type(4)));

#define AS1 __attribute__((address_space(1)))
#define AS3 __attribute__((address_space(3)))

__device__ __forceinline__ void glds16(const bf16* g, bf16* l) {
    __builtin_amdgcn_global_load_lds((const AS1 void*)g, (AS3 void*)l, 16, 0, 0);
}

// =====================================================================
// Input dtype detector: flag=0 -> bf16 inputs, flag=1 -> fp32 inputs.
// =====================================================================
__global__ void detect_dtype(const uint16_t* __restrict__ x, int* __restrict__ flag) {
    __shared__ int cnt;
    if (threadIdx.x == 0) cnt = 0;
    __syncthreads();
    int local = 0;
    for (int i = threadIdx.x; i < 512; i += 256) {
        uint16_t u = x[i];
        int e = (u >> 7) & 0xFF;
        if (e >= 96 && e <= 159) local++;
    }
    atomicAdd(&cnt, local);
    __syncthreads();
    if (threadIdx.x == 0) *flag = (cnt >= 461) ? 0 : 1;
}

// fused fp32->bf16 converts for x / w_attn / w_proj (no-op when flag==0)
#define NX8  (MT * CC / 8)          // 524288
#define NWA8 (C3 * CC / 8)          // 393216
#define NWP8 (CC * CC / 8)          // 131072
__global__ __launch_bounds__(256)
void convert_all(const float* __restrict__ x, const float* __restrict__ wa,
                 const float* __restrict__ wp, bf16* __restrict__ xd,
                 bf16* __restrict__ wad, bf16* __restrict__ wpd,
                 const int* __restrict__ flag) {
    if (*flag == 0) return;
    long i = (long)blockIdx.x * 256 + threadIdx.x;
    const float* s; bf16* d; long off;
    if (i < NX8)             { s = x;  d = xd;  off = i; }
    else if (i < NX8 + NWA8) { s = wa; d = wad; off = i - NX8; }
    else                     { s = wp; d = wpd; off = i - NX8 - NWA8; }
    const float4* sp = reinterpret_cast<const float4*>(s) + off * 2;
    float4 a = sp[0], b = sp[1];
    bf16x8 r;
    r[0] = (bf16)a.x; r[1] = (bf16)a.y; r[2] = (bf16)a.z; r[3] = (bf16)a.w;
    r[4] = (bf16)b.x; r[5] = (bf16)b.y; r[6] = (bf16)b.z; r[7] = (bf16)b.w;
    reinterpret_cast<bf16x8*>(d)[off] = r;
}

// =====================================================================
// GEMM 128x128: C = A*B^T, dbuf single-barrier pipeline. Split store:
// col-blocks >= split_col write V directly in Vt layout (sigma-packed):
// tloc = mi*16+quad*4+r -> sigma(tloc) = quad*16+mi*4+r (r contiguous,
// 8B packed store). Kills the separate vtranspose pass.
// =====================================================================
__global__ __launch_bounds__(256)
void gemm_bt(const bf16* __restrict__ A0, const bf16* __restrict__ A1,
             const bf16* __restrict__ B0, const bf16* __restrict__ B1,
             void* __restrict__ Cmain, bf16* __restrict__ Cv,
             const int* __restrict__ flag,
             int M, int N, int K, int lda, int ldb, int ldc,
             int split_col, int cf32_dyn) {
    __shared__ bf16 As[2][128 * 32];
    __shared__ bf16 Bs[2][128 * 32];

    const int f = *flag;
    const bf16* A = f ? A1 : A0;
    const bf16* B = f ? B1 : B0;
    const int cf32 = cf32_dyn & f;

    const int tid  = threadIdx.x;
    const int lane = tid & 63;
    const int wave = tid >> 6;
    const int wm   = wave >> 1;
    const int wn   = wave & 1;
    const int quad = lane >> 4;
    const int l16  = lane & 15;

    const int row0 = blockIdx.y * 128;
    const int col0 = blockIdx.x * 128;

    const int srow = tid >> 2;
    const int skk  = (tid & 3) * 8;

    const bf16* Ap = A + (long)(row0 + srow) * lda + skk;
    const bf16* Bp = B + (long)(col0 + srow) * ldb + skk;

    auto stage = [&](int k0, int buf) {
        glds16(Ap + k0,                  &As[buf][wave * 512]);
        glds16(Ap + (long)64 * lda + k0, &As[buf][wave * 512 + 2048]);
        glds16(Bp + k0,                  &Bs[buf][wave * 512]);
        glds16(Bp + (long)64 * ldb + k0, &Bs[buf][wave * 512 + 2048]);
    };

    f32x4 acc[4][4] = {};
    stage(0, 0);

    for (int k0 = 0; k0 < K; k0 += 32) {
        const int buf = (k0 >> 5) & 1;
        __syncthreads();
        if (k0 + 32 < K) stage(k0 + 32, buf ^ 1);

        const bf16* Ac = As[buf];
        const bf16* Bc = Bs[buf];
        bf16x8 af[4], bfv[4];
#pragma unroll
        for (int mi = 0; mi < 4; ++mi)
            af[mi] = *reinterpret_cast<const bf16x8*>(&Ac[(wm * 64 + mi * 16 + l16) * 32 + quad * 8]);
#pragma unroll
        for (int ni = 0; ni < 4; ++ni)
            bfv[ni] = *reinterpret_cast<const bf16x8*>(&Bc[(wn * 64 + ni * 16 + l16) * 32 + quad * 8]);
#pragma unroll
        for (int mi = 0; mi < 4; ++mi)
#pragma unroll
            for (int ni = 0; ni < 4; ++ni)
                acc[mi][ni] = __builtin_amdgcn_mfma_f32_16x16x32_bf16(af[mi], bfv[ni], acc[mi][ni], 0, 0, 0);
    }

    if (split_col < 0 || col0 < split_col) {
        // main store (C/D layout: col=l16, row=quad*4+reg)
#pragma unroll
        for (int mi = 0; mi < 4; ++mi)
#pragma unroll
            for (int ni = 0; ni < 4; ++ni)
#pragma unroll
                for (int r = 0; r < 4; ++r) {
                    int row = row0 + wm * 64 + mi * 16 + quad * 4 + r;
                    int col = col0 + wn * 64 + ni * 16 + l16;
                    float v = acc[mi][ni][r];
                    if (cf32) ((float*)Cmain)[(long)row * ldc + col] = v;
                    else      ((bf16*)Cmain)[(long)row * ldc + col] = (bf16)v;
                }
    } else {
        // V store in Vt[bh][d][tc*64 + sigma(tloc)] layout
        const int h  = (col0 - split_col + wn * 64) >> 6;   // wave-uniform
        const int bq = row0 >> 11;
        const int tc = ((row0 & 2047) >> 6) + wm;
#pragma unroll
        for (int ni = 0; ni < 4; ++ni) {
            long vrow = (long)(bq * NH + h) * 64 + ni * 16 + l16;
#pragma unroll
            for (int mi = 0; mi < 4; ++mi) {
                bf16 outv[4];
#pragma unroll
                for (int r = 0; r < 4; ++r) outv[r] = (bf16)acc[mi][ni][r];
                *reinterpret_cast<uint2*>(&Cv[vrow * 2048 + tc * 64 + quad * 16 + mi * 4]) =
                    *reinterpret_cast<uint2*>(outv);
            }
        }
    }
}

// =====================================================================
// GEMM 128x64 (gemm2): grid 512 = 2 blocks/CU. acc[4][2].
// =====================================================================
__global__ __launch_bounds__(256)
void gemm_bt64(const bf16* __restrict__ A0, const bf16* __restrict__ A1,
               const bf16* __restrict__ B0, const bf16* __restrict__ B1,
               void* __restrict__ C, const int* __restrict__ flag,
               int M, int N, int K, int lda, int ldb, int ldc, int cf32_dyn) {
    __shared__ bf16 As[2][128 * 32];
    __shared__ bf16 Bs[2][64 * 32];

    const int f = *flag;
    const bf16* A = f ? A1 : A0;
    const bf16* B = f ? B1 : B0;
    const int cf32 = cf32_dyn & f;

    const int tid  = threadIdx.x;
    const int lane = tid & 63;
    const int wave = tid >> 6;
    const int wm   = wave >> 1;
    const int wn   = wave & 1;
    const int quad = lane >> 4;
    const int l16  = lane & 15;

    const int row0 = blockIdx.y * 128;
    const int col0 = blockIdx.x * 64;

    const int srow = tid >> 2;
    const int skk  = (tid & 3) * 8;

    const bf16* Ap = A + (long)(row0 + srow) * lda + skk;
    const bf16* Bp = B + (long)(col0 + srow) * ldb + skk;

    auto stage = [&](int k0, int buf) {
        glds16(Ap + k0,                  &As[buf][wave * 512]);
        glds16(Ap + (long)64 * lda + k0, &As[buf][wave * 512 + 2048]);
        glds16(Bp + k0,                  &Bs[buf][wave * 512]);
    };

    f32x4 acc[4][2] = {};
    stage(0, 0);

    for (int k0 = 0; k0 < K; k0 += 32) {
        const int buf = (k0 >> 5) & 1;
        __syncthreads();
        if (k0 + 32 < K) stage(k0 + 32, buf ^ 1);

        const bf16* Ac = As[buf];
        const bf16* Bc = Bs[buf];
        bf16x8 af[4], bfv[2];
#pragma unroll
        for (int mi = 0; mi < 4; ++mi)
            af[mi] = *reinterpret_cast<const bf16x8*>(&Ac[(wm * 64 + mi * 16 + l16) * 32 + quad * 8]);
#pragma unroll
        for (int ni = 0; ni < 2; ++ni)
            bfv[ni] = *reinterpret_cast<const bf16x8*>(&Bc[(wn * 32 + ni * 16 + l16) * 32 + quad * 8]);
#pragma unroll
        for (int mi = 0; mi < 4; ++mi)
#pragma unroll
            for (int ni = 0; ni < 2; ++ni)
                acc[mi][ni] = __builtin_amdgcn_mfma_f32_16x16x32_bf16(af[mi], bfv[ni], acc[mi][ni], 0, 0, 0);
    }

#pragma unroll
    for (int mi = 0; mi < 4; ++mi)
#pragma unroll
        for (int ni = 0; ni < 2; ++ni)
#pragma unroll
            for (int r = 0; r < 4; ++r) {
                int row = row0 + wm * 64 + mi * 16 + quad * 4 + r;
                int col = col0 + wn * 32 + ni * 16 + l16;
                float v = acc[mi][ni][r];
                if (cf32) ((float*)C)[(long)row * ldc + col] = v;
                else      ((bf16*)C)[(long)row * ldc + col] = (bf16)v;
            }
}

// =====================================================================
// Per-(bh,kt) V tile sums from Vt rows (sigma permutes within a tile ->
// sum invariant). 1024 blocks, coalesced 32B/thread.
// =====================================================================
__global__ __launch_bounds__(256)
void vtile2(const bf16* __restrict__ Vt, float* __restrict__ Vtile) {
    const int kt = blockIdx.x, bh = blockIdx.y;
    const int tid = threadIdx.x;
    const int d = tid >> 2, part = tid & 3;
    const bf16* p = Vt + ((long)bh * 64 + d) * 2048 + kt * 64 + part * 16;
    float s = 0.f;
#pragma unroll
    for (int i = 0; i < 2; ++i) {
        bf16x8 v = *reinterpret_cast<const bf16x8*>(p + i * 8);
#pragma unroll
        for (int j = 0; j < 8; ++j) s += (float)v[j];
    }
    s += __shfl_xor(s, 1, 64);
    s += __shfl_xor(s, 2, 64);
    if (part == 0) Vtile[((long)bh * 32 + kt) * 64 + d] = s;
}

// Suffix over 64-key tiles (tiny).
__global__ void vts_suffix(const float* __restrict__ Vtile, float* __restrict__ Vts) {
    const int bh = blockIdx.x, d = threadIdx.x;
    Vts[((long)bh * 33 + 32) * 64 + d] = 0.f;
    float acc = 0.f;
    for (int kt = 31; kt >= 0; --kt) {
        acc += Vtile[((long)bh * 32 + kt) * 64 + d];
        Vts[((long)bh * 33 + kt) * 64 + d] = acc;
    }
}

// =====================================================================
// Flash attention v6: KEY-SPLIT waves, hardened. 64q x 64k per block,
// 4 waves; wave w owns keys [16w,16w+16). K LDS reads cut 8->2 b128
// per wave-tile; V fragments read with v1-VERBATIM addressing (two
// uint4 reads at (2q)^sx/(2q+1)^sx chunks) then wave-uniform static
// select of the wave's s16x4 slice -> per wave-tile 10 b128 vs v1's 16
// (block-tile LDS reads 64KB -> 40KB). Cross-wave O/lp reduce via
// rotation-indexed LDS scratch aliasing the pipeline buffers.
// =====================================================================
__global__ __launch_bounds__(256, 2)
void attn(bf16* __restrict__ qk, const bf16* __restrict__ Vt,
          const float* __restrict__ Vts) {
    __shared__ __align__(16) char smem[52224];

    const int tid  = threadIdx.x;
    const int lane = tid & 63;
    const int w    = tid >> 6;              // wave = key-group owner
    const int quad = lane >> 4;
    const int l16  = lane & 15;

    const int f2   = blockIdx.x;            // 0..1023
    const int xcd  = f2 & 7;
    const int slot = f2 >> 3;               // 0..127
    const int u    = slot & 3;              // {b, h&1}
    const int chunk = 31 - (slot >> 2);     // heavy first
    const int h = xcd * 2 + (u & 1);        // producer XCD = h>>1
    const int b = u >> 1;
    const int bh = b * 16 + h;
    const int q0 = chunk * 64;
    const long rbase = (long)b * TT;
    const int ktend = chunk + 1;

    // Q fragments: ALL 64 q-rows, in registers (8 x bf16x8 = 32 VGPR)
    bf16x8 qf[4][2];
#pragma unroll
    for (int qg = 0; qg < 4; ++qg) {
        const bf16* qp = qk + (rbase + q0 + qg * 16 + l16) * 2048 + h * HS;
        qf[qg][0] = *reinterpret_cast<const bf16x8*>(qp + quad * 8);
        qf[qg][1] = *reinterpret_cast<const bf16x8*>(qp + 32 + quad * 8);
    }

    f32x4 O[4][4] = {};     // [dg][qg] partial over wave's 16 keys
    float lp[4] = {};       // [qg] partial row-sums

    // staging (identical layout to v1: XOR-swizzled chunks)
    const int rl  = lane >> 3;
    const int cs  = (lane & 7) ^ rl;
    const int row0dma = w * 16 + rl;
    const bf16* kgb = qk + (rbase + row0dma) * 2048 + CC + h * HS + cs * 8;
    const bf16* vgb = Vt + ((long)(b * NH + h) * 64 + row0dma) * 2048 + cs * 8;
    const int sx = l16 & 7;

    auto KsB = [&](int bi) { return (bf16*)(smem + bi * 8192); };
    auto VsB = [&](int bi) { return (bf16*)(smem + 16384 + bi * 8192); };

    auto stage = [&](int kt, int bi) {
        glds16(kgb + (long)(kt * 64) * 2048,     KsB(bi) + w * 1024);
        glds16(kgb + (long)(kt * 64 + 8) * 2048, KsB(bi) + w * 1024 + 512);
        glds16(vgb + kt * 64,                    VsB(bi) + w * 1024);
        glds16(vgb + 8 * 2048 + kt * 64,         VsB(bi) + w * 1024 + 512);
    };

    stage(0, 0);

    for (int kt = 0; kt < ktend; ++kt) {
        const int buf = kt & 1;
        __syncthreads();
        if (kt + 1 < ktend) stage(kt + 1, buf ^ 1);

        const bf16* Kc = KsB(buf);
        const bf16* Vc = VsB(buf);

        // K slice: wave's 16 keys x 64 d -> 2 x ds_read_b128
        const bf16x8 kf0 = *reinterpret_cast<const bf16x8*>(
            &Kc[(w * 16 + l16) * 64 + ((quad ^ sx) * 8)]);
        const bf16x8 kf1 = *reinterpret_cast<const bf16x8*>(
            &Kc[(w * 16 + l16) * 64 + (((4 + quad) ^ sx) * 8)]);

        // V fragments: v1-verbatim reads, static select of wave's slice
        s16x4 vf[4];
#pragma unroll
        for (int dg = 0; dg < 4; ++dg) {
            const int vrow = dg * 16 + l16;
            union { uint4 u4; s16x4 s[2]; } ua, ub;
            ua.u4 = *reinterpret_cast<const uint4*>(&Vc[vrow * 64 + (((2 * quad) ^ sx) * 8)]);
            ub.u4 = *reinterpret_cast<const uint4*>(&Vc[vrow * 64 + (((2 * quad + 1) ^ sx) * 8)]);
            if      (w == 0) vf[dg] = ua.s[0];
            else if (w == 1) vf[dg] = ua.s[1];
            else if (w == 2) vf[dg] = ub.s[0];
            else             vf[dg] = ub.s[1];
        }

        // QK^T: S[qg] = K_w(16k x 64d) x Q_qg(16q x 64d)
        f32x4 S[4] = {};
        __builtin_amdgcn_s_setprio(1);
#pragma unroll
        for (int qg = 0; qg < 4; ++qg) {
            S[qg] = __builtin_amdgcn_mfma_f32_16x16x32_bf16(kf0, qf[qg][0], S[qg], 0, 0, 0);
            S[qg] = __builtin_amdgcn_mfma_f32_16x16x32_bf16(kf1, qf[qg][1], S[qg], 0, 0, 0);
        }
        __builtin_amdgcn_s_setprio(0);

        const bool dtile = (kt == ktend - 1);
        const int klbase = w * 16 + quad * 4;
        s16x4 pk[4];
#pragma unroll
        for (int qg = 0; qg < 4; ++qg) {
#pragma unroll
            for (int r = 0; r < 4; ++r) {
                float p = __builtin_exp2f(S[qg][r] * SCL2);
                if (dtile) {
                    int kl = klbase + r;
                    int ql = qg * 16 + l16;
                    p = (kl > ql) ? E10 : p;
                }
                lp[qg] += p;
                union { bf16 b_; short s_; } u2;
                u2.b_ = (bf16)p;
                pk[qg][r] = u2.s_;
            }
        }

        // PV: O[dg][qg] += V_w(16d x 16k) x P_w(16k x 16q)
        __builtin_amdgcn_s_setprio(1);
#pragma unroll
        for (int dg = 0; dg < 4; ++dg)
#pragma unroll
            for (int qg = 0; qg < 4; ++qg)
                O[dg][qg] = __builtin_amdgcn_mfma_f32_16x16x16bf16_1k(
                    vf[dg], pk[qg], O[dg][qg], 0, 0, 0);
        __builtin_amdgcn_s_setprio(0);
    }

    // cross-quad lp reduce (each lane: sum over wave's 16 keys, per qg)
#pragma unroll
    for (int qg = 0; qg < 4; ++qg) {
        lp[qg] += __shfl_xor(lp[qg], 16, 64);
        lp[qg] += __shfl_xor(lp[qg], 32, 64);
    }

    // ---- cross-wave reduction (once per block) ----
    __syncthreads();                         // pipeline done; alias scratch
    f32x4* redO = (f32x4*)smem;              // [qg][k=0..2][dg][lane] 48KB
    float* redL = (float*)(smem + 49152);    // [qg][k][64]             3KB

#pragma unroll
    for (int qg = 0; qg < 4; ++qg) {
        if (qg != w) {                       // wave-uniform branch
            const int k = (w - qg - 1) & 3;  // 0..2, rotation index
#pragma unroll
            for (int dg = 0; dg < 4; ++dg)
                redO[((qg * 3 + k) * 4 + dg) * 64 + lane] = O[dg][qg];
            if (quad == 0) redL[(qg * 3 + k) * 64 + l16] = lp[qg];
        }
    }
    __syncthreads();

    // own q-group: zero-init + accumulate (static indexing throughout)
    f32x4 Of[4] = {};
    float lpf = 0.f;
#pragma unroll
    for (int qg = 0; qg < 4; ++qg) {
        if (qg == w) {
#pragma unroll
            for (int dg = 0; dg < 4; ++dg) Of[dg] += O[dg][qg];
            lpf += lp[qg];
        }
    }
#pragma unroll
    for (int k = 0; k < 3; ++k) {
#pragma unroll
        for (int dg = 0; dg < 4; ++dg)
            Of[dg] += redO[((w * 3 + k) * 4 + dg) * 64 + lane];
        lpf += redL[(w * 3 + k) * 64 + l16];
    }

    // epilogue: wave w writes q-group w
    const int nfut = TT - ktend * 64;
    const float l = lpf + (float)nfut * E10;
    const float invl = 1.0f / l;
    const float* vfp = Vts + ((long)bh * 33 + ktend) * 64;

    bf16* yp = qk + (rbase + q0 + w * 16 + l16) * 2048 + h * HS;
#pragma unroll
    for (int dg = 0; dg < 4; ++dg) {
        bf16 outv[4];
#pragma unroll
        for (int r = 0; r < 4; ++r) {
            float o = Of[dg][r] + E10 * vfp[dg * 16 + quad * 4 + r];
            outv[r] = (bf16)(o * invl);
        }
        *reinterpret_cast<uint2*>(yp + dg * 16 + quad * 4) =
            *reinterpret_cast<uint2*>(outv);
    }
}

// =====================================================================
extern "C" void kernel_launch(void* const* d_in, const int* in_sizes, int n_in,
                              void* d_out, int out_size, void* d_ws, size_t ws_size,
                              hipStream_t stream) {
    const void* x      = d_in[0];
    const void* w_attn = d_in[1];
    const void* w_proj = d_in[2];

    // ws (~27.8 MB): qk | Vt | flag | Vts | wp_cvt | Vtile
    char* ws = (char*)d_ws;
    bf16*  qk     = (bf16*)ws;                                    // 16,777,216 B
    bf16*  Vt     = (bf16*)(ws + (size_t)MT * 2048 * 2);          //  8,388,608 B
    char*  p2     = ws + (size_t)MT * 2048 * 2 + (size_t)32 * 64 * 2048 * 2;
    int*   flag   = (int*)p2;
    float* Vts    = (float*)(p2 + 256);                           //    270,336 B
    bf16*  wp_cvt = (bf16*)(p2 + 256 + 32 * 33 * 64 * 4);         //  2,097,152 B
    float* Vtile  = (float*)((char*)wp_cvt + (size_t)CC * CC * 2);//    262,144 B

    // d_out scratch (dead-by-ordering): x_cvt/wa_cvt consumed by gemm1;
    // gemm2 is the only writer of d_out afterwards.
    bf16* x_cvt  = (bf16*)d_out;
    bf16* wa_cvt = (bf16*)d_out + (size_t)MT * CC;

    detect_dtype<<<1, 256, 0, stream>>>((const uint16_t*)x, flag);
    convert_all<<<(NX8 + NWA8 + NWP8) / 256, 256, 0, stream>>>(
        (const float*)x, (const float*)w_attn, (const float*)w_proj,
        x_cvt, wa_cvt, wp_cvt, flag);

    // gemm1: qkv projection. cols<2048 (Q,K) -> qk (ldc 2048);
    // cols>=2048 (V) -> Vt directly (sigma-packed layout).
    gemm_bt<<<dim3(C3 / 128, MT / 128), 256, 0, stream>>>(
        (const bf16*)x, x_cvt, (const bf16*)w_attn, wa_cvt, qk, Vt, flag,
        MT, C3, CC, CC, CC, /*ldc*/2048, /*split*/2048, /*cf32*/0);

    // V tile sums + suffix (soft-mask correction inputs)
    vtile2<<<dim3(32, BSZ * NH), 256, 0, stream>>>(Vt, Vtile);
    vts_suffix<<<dim3(BSZ * NH), dim3(64), 0, stream>>>(Vtile, Vts);

    // attention (producer-XCD-aligned grid); y overwrites Q columns of qk
    attn<<<dim3(1024), 256, 0, stream>>>(qk, Vt, Vts);

    // gemm2: out = y @ w_proj^T  [4096, 1024] — 128x64 tiles
    gemm_bt64<<<dim3(CC / 64, MT / 128), 256, 0, stream>>>(
        qk, qk, (const bf16*)w_proj, wp_cvt, d_out, flag,
        MT, CC, CC, /*lda*/2048, CC, CC, /*cf32*/1);
}